// Round 5
// baseline (412.096 us; speedup 1.0000x reference)
//
#include <hip/hip_runtime.h>
#include <hip/hip_bf16.h>
#include <math.h>

#define V_TOT 60000
#define VPB 4
#define NBLK (V_TOT / VPB)   // 15000

typedef short  s16x8 __attribute__((ext_vector_type(8)));
typedef float  f32x4 __attribute__((ext_vector_type(4)));

// ---- ws: tile-major bf16 weights (ushort offsets). Tile(nt,k) = 512 elems:
// elem[lane*8+i] = W[nt*16+(lane&15)][k*32+(lane>>4)*8+i]
#define WS_EW0 0        // NT16 KS5
#define WS_EW1 40960    // NT16 KS8
#define WS_EW2 106496   // NT8  KS8
#define WS_EW3 139264   // NT8  KS4
#define WS_EW4 155648   // NT8  KS4
#define WS_EW5 172032   // NT1  KS4
#define WS_PW0 174080   // NT4  KS1
#define WS_PW1 176128   // NT2  KS2
#define WS_PW2 178176   // NT2  KS1
#define WS_PW3 179200   // NT1  KS1
#define WS_TW0 179712   // NT4  KS1
#define WS_TW1 181760   // NT2  KS2
#define WS_TW2 183808   // NT2  KS1
#define WS_TW3 184832   // NT1  KS1

// ---- LDS byte offsets (total 40848 <= 40960 -> 4 blocks/CU) ----
#define L_ACTA 0        // [32][264] bf16 = 16896 ; encf[4][80] f32 + oencf[4][24] f32 alias
#define L_ENCF 0
#define L_OENC 1280
#define L_ACTB 16896    // [32][264] bf16 ; a0[32][160] alias; ph0[32][72]@16896; ph1[32][40]@21504; ph2@24064
#define L_PH0  16896
#define L_PH1  21504
#define L_PH2  24064
#define L_A0P  33792    // [32][32] bf16 = 2048 ; tB [16][40] aliases here (T2+)
#define L_TB   33792
#define L_A0T  35840    // [16][32] bf16 = 1024
#define L_TA   36864    // [16][72] bf16 = 2304 ; tC [16][40] aliases here (T3+)
#define L_TC   36864
#define L_VERT 39168    // [4][6] f32 = 96
#define L_FEATB 39264   // [8][64] bf16 = 1024 (feats 0..61, stride 64)
#define L_EXPR 40288    // [32][3] f32 = 384
#define L_TMPL 40672    // [4][3] f32 = 48
#define L_POSW 40720    // [32] f32 = 128
#define SMEM_BYTES 40848

struct Params {
  const float* vertices; const float* features;
  const float* eb0; const float* eb1; const float* eb2; const float* eb3;
  const float* eb4; const float* eb5;
  const float* tb0; const float* tb1; const float* tb2; const float* tb3;
  const float* pb0; const float* pb1; const float* pb2; const float* pb3;
  const float* torigin; const float* scale;
  const ushort* wsb;
  float* out;
};

__device__ __forceinline__ float silu_f(float x) {
  float e = __expf(-x);
  return x * __builtin_amdgcn_rcpf(1.f + e);
}
__device__ __forceinline__ float sigm_f(float x) {
  return __builtin_amdgcn_rcpf(1.f + __expf(-x));
}
__device__ __forceinline__ ushort f2bf(float f) {
  unsigned u = __float_as_uint(f);
  return (ushort)((u + 0x7fffu + ((u >> 16) & 1u)) >> 16);
}
__device__ __forceinline__ unsigned pack2bf(float a, float b) {
  __hip_bfloat162 h = __float22bfloat162_rn(float2{a, b});
  unsigned u; __builtin_memcpy(&u, &h, 4); return u;
}

// Big layer, 8 waves: wave w owns mt = w&1, nt_s = (w>>1) + s*4 (s < NT_TOT/4).
// Weights are the A-operand, acts B: D[feat][pt]; packed b64 epilogue.
template<int KS, int NT_TOT, int INSTR, int OUTSTR>
__device__ __forceinline__ void big_layer_T(const ushort* __restrict__ Wt,
                                            const float* __restrict__ bias,
                                            const ushort* inb, ushort* outb,
                                            int lane, int wv)
{
  constexpr int SLOTS = NT_TOT / 4;
  const int r16 = lane & 15, g = lane >> 4;
  const int mt = wv & 1;
  const ushort* ab = inb + (mt * 16 + r16) * INSTR + g * 8;
  const ushort* wb[SLOTS];
  f32x4 acc[SLOTS];
  #pragma unroll
  for (int s = 0; s < SLOTS; s++) {
    const int nt = (wv >> 1) + s * 4;
    wb[s] = Wt + (size_t)nt * KS * 512 + lane * 8;
    const float4 bv = *(const float4*)(bias + nt * 16 + g * 4);
    acc[s] = (f32x4){bv.x, bv.y, bv.z, bv.w};
  }
  #pragma unroll
  for (int k = 0; k < KS; k++) {
    s16x8 bf = *(const s16x8*)(ab + k * 32);
    #pragma unroll
    for (int s = 0; s < SLOTS; s++) {
      s16x8 aw = *(const s16x8*)(wb[s] + k * 512);
      acc[s] = __builtin_amdgcn_mfma_f32_16x16x32_bf16(aw, bf, acc[s], 0, 0, 0);
    }
  }
  #pragma unroll
  for (int s = 0; s < SLOTS; s++) {
    const int nt = (wv >> 1) + s * 4;
    uint2 w;
    w.x = pack2bf(silu_f(acc[s][0]), silu_f(acc[s][1]));
    w.y = pack2bf(silu_f(acc[s][2]), silu_f(acc[s][3]));
    *(uint2*)(outb + (mt * 16 + r16) * OUTSTR + nt * 16 + g * 4) = w;
  }
}

// one swapped 16x16 tile: D[feat][pt]
template<int KS, int INSTR>
__device__ __forceinline__ f32x4 tile_mm_T(const ushort* __restrict__ Wt,
                                           const ushort* inb, int mt, int lane, f32x4 binit)
{
  const int r16 = lane & 15, g = lane >> 4;
  f32x4 acc = binit;
  #pragma unroll
  for (int k = 0; k < KS; k++) {
    s16x8 aw = *(const s16x8*)(Wt + k * 512 + lane * 8);
    s16x8 bf = *(const s16x8*)(inb + (mt * 16 + r16) * INSTR + k * 32 + g * 8);
    acc = __builtin_amdgcn_mfma_f32_16x16x32_bf16(aw, bf, acc, 0, 0, 0);
  }
  return acc;
}

__global__ void conv_w(const float* __restrict__ src, ushort* __restrict__ dst,
                       int NT, int KS, int Ksrc, int Kused, int Nused)
{
  int idx = blockIdx.x * 256 + threadIdx.x;
  if (idx >= NT * KS * 512) return;
  int t = idx >> 9, l = (idx >> 3) & 63, i = idx & 7;
  int nt = t / KS, k = t - nt * KS;
  int row = nt * 16 + (l & 15);
  int kk = k * 32 + (l >> 4) * 8 + i;
  float v = (row < Nused && kk < Kused) ? src[row * Ksrc + kk] : 0.f;
  dst[idx] = f2bf(v);
}

extern "C" __global__ __launch_bounds__(512, 8)
void nbs_kernel(Params P)
{
  extern __shared__ char sm[];
  ushort* actAb = (ushort*)(sm + L_ACTA);
  float*  encf  = (float*)(sm + L_ENCF);   // [4][80]
  float*  oencf = (float*)(sm + L_OENC);   // [4][24]
  ushort* a0    = (ushort*)(sm + L_ACTB);  // [32][160]
  ushort* actBb = (ushort*)(sm + L_ACTB);
  ushort* ph0b  = (ushort*)(sm + L_PH0);   // [32][72]
  ushort* ph1b  = (ushort*)(sm + L_PH1);   // [32][40]
  ushort* ph2b  = (ushort*)(sm + L_PH2);   // [32][40]
  ushort* a0p   = (ushort*)(sm + L_A0P);   // [32][32]
  ushort* a0t   = (ushort*)(sm + L_A0T);   // [16][32]
  ushort* tAl   = (ushort*)(sm + L_TA);    // [16][72]
  ushort* tBl   = (ushort*)(sm + L_TB);    // [16][40]
  ushort* tCl   = (ushort*)(sm + L_TC);    // [16][40]
  float*  vertl = (float*)(sm + L_VERT);   // [4][6]
  ushort* featb = (ushort*)(sm + L_FEATB); // [8][64]
  float*  exprv = (float*)(sm + L_EXPR);   // [32][3]
  float*  tmplv = (float*)(sm + L_TMPL);   // [4][3]
  float*  posew = (float*)(sm + L_POSW);   // [32]

  const int tid  = threadIdx.x;
  const int lane = tid & 63;
  const int wv   = __builtin_amdgcn_readfirstlane(tid >> 6);
  const int r16  = lane & 15, g = lane >> 4;
  const int v0   = blockIdx.x * VPB;
  const ushort* ws = P.wsb;

  // ---- P01: stage featb (bf16), vertl, compute encodings from global ----
  {
    uint* fbu = (uint*)featb;
    if (tid < 256) {
      int b = tid >> 5, q = tid & 31;
      int e0 = q * 2, e1 = e0 + 1;
      float s0 = (e0 < 62) ? P.features[b * 62 + e0] : 0.f;
      float s1 = (e1 < 62) ? P.features[b * 62 + e1] : 0.f;
      fbu[b * 32 + q] = pack2bf(s0, s1);
    }
    if (tid < VPB * 6) vertl[tid] = P.vertices[(size_t)v0 * 6 + tid];
    int i2 = tid - 256;
    if (i2 >= 0 && i2 < 4 * 80) {
      int v = i2 / 80, e = i2 - v * 80;
      float val = 0.f;
      if (e < 6) val = P.vertices[(size_t)(v0 + v) * 6 + e];
      else if (e < 78) {
        int r = e - 6, k = r / 12, q = r - k * 12;
        float x = P.vertices[(size_t)(v0 + v) * 6 + (q < 6 ? q : q - 6)] * (float)(1 << k);
        val = (q < 6) ? __sinf(x) : __cosf(x);
      }
      encf[i2] = val;
    }
    int i3 = tid - (256 + 320);
    if (i3 >= 0 && i3 < 4 * 24) {
      int v = i3 / 24, e = i3 - v * 24;
      float val = 0.f;
      if (e < 3) val = P.vertices[(size_t)(v0 + v) * 6 + e];
      else if (e < 21) {
        int r = e - 3, k = r / 6, q = r - k * 6;
        float x = P.vertices[(size_t)(v0 + v) * 6 + (q < 3 ? q : q - 3)] * (float)(1 << k);
        val = (q < 3) ? __sinf(x) : __cosf(x);
      }
      oencf[i3] = val;
    }
  }
  __syncthreads();

  // ---- P2: build a0 / a0p / a0t ----
  {
    uint* a0u = (uint*)a0;            // [32][80]
    uint* fbu = (uint*)featb;
    ushort* fbs = featb;
    for (int idx = tid; idx < 32 * 80; idx += 512) {
      int p = idx / 80, q = idx - p * 80, vl = p >> 3, b = p & 7;
      uint u;
      if (q < 39)       u = pack2bf(encf[vl * 80 + 2 * q], encf[vl * 80 + 2 * q + 1]);
      else if (q < 65)  u = fbu[b * 32 + (q - 39)];
      else if (q == 65) u = (uint)fbs[b * 64 + 52];
      else              u = 0u;
      a0u[p * 80 + q] = u;
    }
    uint* a0pu = (uint*)a0p;          // [32][16]
    if (tid < 512) {
      int p = tid >> 4, q = tid & 15, vl = p >> 3, b = p & 7;
      uint u;
      if (q < 10)       u = pack2bf(oencf[vl * 24 + 2 * q], oencf[vl * 24 + 2 * q + 1]);
      else if (q == 10) u = (uint)f2bf(oencf[vl * 24 + 20]) | ((uint)fbs[b * 64 + 53] << 16);
      else if (q == 11) u = fbu[b * 32 + 27];   // feats 54,55
      else if (q == 12) u = fbu[b * 32 + 28];   // feats 56,57
      else if (q == 13) u = (uint)fbs[b * 64 + 58];
      else              u = 0u;
      a0pu[p * 16 + q] = u;
    }
    uint* a0tu = (uint*)a0t;          // [16][16]
    if (tid < 256) {
      int v = tid >> 4, q = tid & 15;
      uint u = 0u;
      if (v < 4) {
        if (q < 10)       u = pack2bf(oencf[v * 24 + 2 * q], oencf[v * 24 + 2 * q + 1]);
        else if (q == 10) u = (uint)f2bf(oencf[v * 24 + 20]);
      }
      a0tu[v * 16 + q] = u;
    }
  }
  __syncthreads();

  // ---- expr MLP L0..L4 ----
  big_layer_T<5, 16, 160, 264>(ws + WS_EW0, P.eb0, a0,    actAb, lane, wv);
  __syncthreads();
  big_layer_T<8, 16, 264, 264>(ws + WS_EW1, P.eb1, actAb, actBb, lane, wv);
  __syncthreads();
  big_layer_T<8,  8, 264, 264>(ws + WS_EW2, P.eb2, actBb, actAb, lane, wv);
  __syncthreads();
  big_layer_T<4,  8, 264, 264>(ws + WS_EW3, P.eb3, actAb, actBb, lane, wv);
  __syncthreads();
  big_layer_T<4,  8, 264, 264>(ws + WS_EW4, P.eb4, actBb, actAb, lane, wv);
  __syncthreads();

  // ---- T1: pose L0 (w0-3, nt=w, mt=0..1) | template t0 (w4-7, nt=w-4) ----
  if (wv < 4) {
    const int nt = wv;
    const float4 bv = *(const float4*)(P.pb0 + nt * 16 + g * 4);
    #pragma unroll
    for (int mt = 0; mt < 2; mt++) {
      f32x4 d = tile_mm_T<1, 32>(ws + WS_PW0 + nt * 512, a0p, mt, lane,
                                 (f32x4){bv.x, bv.y, bv.z, bv.w});
      uint2 w;
      w.x = pack2bf(silu_f(d[0]), silu_f(d[1]));
      w.y = pack2bf(silu_f(d[2]), silu_f(d[3]));
      *(uint2*)(ph0b + (mt * 16 + r16) * 72 + nt * 16 + g * 4) = w;
    }
  } else {
    const int nt = wv - 4;
    const float4 bv = *(const float4*)(P.tb0 + nt * 16 + g * 4);
    f32x4 d = tile_mm_T<1, 32>(ws + WS_TW0 + nt * 512, a0t, 0, lane,
                               (f32x4){bv.x, bv.y, bv.z, bv.w});
    uint2 w;
    w.x = pack2bf(silu_f(d[0]), silu_f(d[1]));
    w.y = pack2bf(silu_f(d[2]), silu_f(d[3]));
    *(uint2*)(tAl + r16 * 72 + nt * 16 + g * 4) = w;
  }
  __syncthreads();

  // ---- T2: pose L1 (w0-3) | expr L5 (w4-5) | template t1 (w6-7) ----
  if (wv < 4) {
    const int nt = wv >> 1, mt = wv & 1;
    const float4 bv = *(const float4*)(P.pb1 + nt * 16 + g * 4);
    f32x4 d = tile_mm_T<2, 72>(ws + WS_PW1 + nt * 2 * 512, ph0b, mt, lane,
                               (f32x4){bv.x, bv.y, bv.z, bv.w});
    uint2 w;
    w.x = pack2bf(silu_f(d[0]), silu_f(d[1]));
    w.y = pack2bf(silu_f(d[2]), silu_f(d[3]));
    *(uint2*)(ph1b + (mt * 16 + r16) * 40 + nt * 16 + g * 4) = w;
  } else if (wv < 6) {
    const int mt = wv - 4;
    f32x4 bi = (f32x4){0.f, 0.f, 0.f, 0.f};
    if (g == 0) bi = (f32x4){P.eb5[0], P.eb5[1], P.eb5[2], 0.f};
    f32x4 d = tile_mm_T<4, 264>(ws + WS_EW5, actAb, mt, lane, bi);
    if (g == 0) {
      exprv[(mt * 16 + r16) * 3 + 0] = d[0];
      exprv[(mt * 16 + r16) * 3 + 1] = d[1];
      exprv[(mt * 16 + r16) * 3 + 2] = d[2];
    }
  } else {
    const int nt = wv - 6;
    const float4 bv = *(const float4*)(P.tb1 + nt * 16 + g * 4);
    f32x4 d = tile_mm_T<2, 72>(ws + WS_TW1 + nt * 2 * 512, tAl, 0, lane,
                               (f32x4){bv.x, bv.y, bv.z, bv.w});
    uint2 w;
    w.x = pack2bf(silu_f(d[0]), silu_f(d[1]));
    w.y = pack2bf(silu_f(d[2]), silu_f(d[3]));
    *(uint2*)(tBl + r16 * 40 + nt * 16 + g * 4) = w;
  }
  __syncthreads();

  // ---- T3: pose L2 (w0-3) | template t2 (w4-5) ----
  if (wv < 4) {
    const int nt = wv >> 1, mt = wv & 1;
    const float4 bv = *(const float4*)(P.pb2 + nt * 16 + g * 4);
    f32x4 d = tile_mm_T<1, 40>(ws + WS_PW2 + nt * 512, ph1b, mt, lane,
                               (f32x4){bv.x, bv.y, bv.z, bv.w});
    uint2 w;
    w.x = pack2bf(silu_f(d[0]), silu_f(d[1]));
    w.y = pack2bf(silu_f(d[2]), silu_f(d[3]));
    *(uint2*)(ph2b + (mt * 16 + r16) * 40 + nt * 16 + g * 4) = w;
  } else if (wv < 6) {
    const int nt = wv - 4;
    const float4 bv = *(const float4*)(P.tb2 + nt * 16 + g * 4);
    f32x4 d = tile_mm_T<1, 40>(ws + WS_TW2 + nt * 512, tBl, 0, lane,
                               (f32x4){bv.x, bv.y, bv.z, bv.w});
    uint2 w;
    w.x = pack2bf(silu_f(d[0]), silu_f(d[1]));
    w.y = pack2bf(silu_f(d[2]), silu_f(d[3]));
    *(uint2*)(tCl + r16 * 40 + nt * 16 + g * 4) = w;
  }
  __syncthreads();

  // ---- T4: pose L3 (w0-1, mt=w) | template t3 (w2) ----
  if (wv < 2) {
    const int mt = wv;
    f32x4 bi = (g == 0) ? (f32x4){P.pb3[0], 0.f, 0.f, 0.f} : (f32x4){0.f, 0.f, 0.f, 0.f};
    f32x4 d = tile_mm_T<1, 40>(ws + WS_PW3, ph2b, mt, lane, bi);
    if (g == 0) posew[mt * 16 + r16] = sigm_f(d[0]);
  } else if (wv == 2) {
    f32x4 bi = (g == 0) ? (f32x4){P.tb3[0], P.tb3[1], P.tb3[2], 0.f}
                        : (f32x4){0.f, 0.f, 0.f, 0.f};
    f32x4 d = tile_mm_T<1, 40>(ws + WS_TW3, tCl, 0, lane, bi);
    if (g == 0 && r16 < 4) {
      tmplv[r16 * 3 + 0] = d[0];
      tmplv[r16 * 3 + 1] = d[1];
      tmplv[r16 * 3 + 2] = d[2];
    }
  }
  __syncthreads();

  // ---- final transform + store (32 points) ----
  if (tid < 32) {
    int p = tid, vl = p >> 3, b = p & 7;
    float ox = P.torigin[0] * 0.1f, oy = P.torigin[1] * 0.1f, oz = P.torigin[2] * 0.1f;
    float sc = P.scale[0];
    float ev0 = vertl[vl * 6 + 0] + exprv[p * 3 + 0] + tmplv[vl * 3 + 0];
    float ev1 = vertl[vl * 6 + 1] + exprv[p * 3 + 1] + tmplv[vl * 3 + 1];
    float ev2 = vertl[vl * 6 + 2] + exprv[p * 3 + 2] + tmplv[vl * 3 + 2];
    float w = posew[p];
    const float* fb = P.features + b * 62;
    float a0a = fb[53] * w;
    float a1a = fb[54] * w;
    float a2a = fb[55] * w;
    float c1 = __cosf(a0a), s1 = __sinf(a0a);
    float c2 = __cosf(a1a), s2 = __sinf(a1a);
    float c3 = __cosf(a2a), s3 = __sinf(a2a);
    float R00 = c2 * c3,                R01 = -c2 * s3,                R02 = s2;
    float R10 = c1 * s3 + s1 * s2 * c3, R11 = c1 * c3 - s1 * s2 * s3,  R12 = -s1 * c2;
    float R20 = s1 * s3 - c1 * s2 * c3, R21 = s1 * c3 + c1 * s2 * s3,  R22 = c1 * c2;
    float l0 = (ev0 - ox) * sc, l1 = (ev1 - oy) * sc, l2 = (ev2 - oz) * sc;
    float o0 = l0 * R00 + l1 * R10 + l2 * R20 + fb[56] + ox;
    float o1 = l0 * R01 + l1 * R11 + l2 * R21 + fb[57] + oy;
    float o2 = l0 * R02 + l1 * R12 + l2 * R22 + fb[58] + oz;
    size_t o = ((size_t)b * V_TOT + (v0 + vl)) * 3;
    P.out[o + 0] = o0; P.out[o + 1] = o1; P.out[o + 2] = o2;
  }
}

extern "C" void kernel_launch(void* const* d_in, const int* in_sizes, int n_in,
                              void* d_out, int out_size, void* d_ws, size_t ws_size,
                              hipStream_t stream)
{
  (void)in_sizes; (void)n_in; (void)out_size; (void)ws_size;
  ushort* wsp = (ushort*)d_ws;

  auto L = [&](const void* s, int woff, int NT, int KS, int Ksrc, int Kused, int Nused) {
    int n = NT * KS * 512;
    hipLaunchKernelGGL(conv_w, dim3((n + 255) / 256), dim3(256), 0, stream,
                       (const float*)s, wsp + woff, NT, KS, Ksrc, Kused, Nused);
  };
  L(d_in[2],  WS_EW0, 16, 5, 131, 131, 256);
  L(d_in[4],  WS_EW1, 16, 8, 256, 256, 256);
  L(d_in[6],  WS_EW2,  8, 8, 256, 256, 128);
  L(d_in[8],  WS_EW3,  8, 4, 128, 128, 128);
  L(d_in[10], WS_EW4,  8, 4, 128, 128, 128);
  L(d_in[12], WS_EW5,  1, 4, 128, 128, 3);
  L(d_in[22], WS_PW0,  4, 1,  27,  27, 64);
  L(d_in[24], WS_PW1,  2, 2,  64,  64, 32);
  L(d_in[26], WS_PW2,  2, 1,  32,  32, 32);
  L(d_in[28], WS_PW3,  1, 1,  32,  32, 1);
  L(d_in[14], WS_TW0,  4, 1,  21,  21, 64);
  L(d_in[16], WS_TW1,  2, 2,  64,  64, 32);
  L(d_in[18], WS_TW2,  2, 1,  32,  32, 32);
  L(d_in[20], WS_TW3,  1, 1,  32,  32, 3);

  Params P;
  P.vertices = (const float*)d_in[0];  P.features = (const float*)d_in[1];
  P.eb0 = (const float*)d_in[3];   P.eb1 = (const float*)d_in[5];
  P.eb2 = (const float*)d_in[7];   P.eb3 = (const float*)d_in[9];
  P.eb4 = (const float*)d_in[11];  P.eb5 = (const float*)d_in[13];
  P.tb0 = (const float*)d_in[15];  P.tb1 = (const float*)d_in[17];
  P.tb2 = (const float*)d_in[19];  P.tb3 = (const float*)d_in[21];
  P.pb0 = (const float*)d_in[23];  P.pb1 = (const float*)d_in[25];
  P.pb2 = (const float*)d_in[27];  P.pb3 = (const float*)d_in[29];
  P.torigin = (const float*)d_in[30];
  P.scale   = (const float*)d_in[31];
  P.wsb = (const ushort*)wsp;
  P.out = (float*)d_out;

  (void)hipFuncSetAttribute((const void*)nbs_kernel,
                            hipFuncAttributeMaxDynamicSharedMemorySize, SMEM_BYTES);
  hipLaunchKernelGGL(nbs_kernel, dim3(NBLK), dim3(512), SMEM_BYTES, stream, P);
}

// Round 6
// 285.242 us; speedup vs baseline: 1.4447x; 1.4447x over previous
//
#include <hip/hip_runtime.h>
#include <hip/hip_bf16.h>
#include <math.h>

#define V_TOT 60000
#define VPB 8
#define NBLK (V_TOT / VPB)   // 7500

typedef short  s16x8 __attribute__((ext_vector_type(8)));
typedef float  f32x4 __attribute__((ext_vector_type(4)));

// ---- ws: tile-major bf16 weights (ushort offsets). Tile(nt,k) = 512 elems:
// elem[lane*8+i] = W[nt*16+(lane&15)][k*32+(lane>>4)*8+i]
#define WS_EW0 0        // NT16 KS3 (enc part only, K=78 pad 96)
#define WS_EW1 40960    // NT16 KS8
#define WS_EW2 106496   // NT8  KS8
#define WS_EW3 139264   // NT8  KS4
#define WS_EW4 155648   // NT8  KS4
#define WS_EW5 172032   // NT1  KS4
#define WS_PW0 174080   // NT4  KS1
#define WS_PW1 176128   // NT2  KS2
#define WS_PW2 178176   // NT2  KS1
#define WS_PW3 179200   // NT1  KS1
#define WS_TW0 179712   // NT4  KS1
#define WS_TW1 181760   // NT2  KS2
#define WS_TW2 183808   // NT2  KS1
#define WS_TW3 184832   // NT1  KS1
#define WS_F   185344   // f32 [8][256] starts here (ushort offset; 4B aligned)

// ---- LDS byte offsets (total 48288 -> 3 blocks/CU) ----
#define L_ACT   0        // [64][264] bf16 = 33792 (in-place act; ph0/ph1/ph2 alias cols 132+)
#define L_U     33792    // [8][260] f32 = 8320   (dead after combine)
#define L_ENC96 42112    // [16][96] bf16 = 3072  (dead after U-mfma)
#define L_OENC  45184    // [8][24] f32 = 768     (dead after PB)
// post-L4 aliases over 33792..:
#define L_A0P   33792    // [64][32] bf16 = 4096
#define L_A0T   37888    // [16][32] bf16 = 1024
#define L_TA    38912    // [16][72] bf16 = 2304
#define L_TB    41216    // [16][40] bf16 = 1280
#define L_TC    42496    // [16][40] bf16 = 1280
#define L_FEATB 45952    // [8][64] bf16 = 1024
#define L_VERT  46976    // [8][6] f32 = 192
#define L_EXPR  47168    // [64][3] f32 = 768
#define L_TMPL  47936    // [8][3] f32 = 96
#define L_POSW  48032    // [64] f32 = 256
#define SMEM_BYTES 48288

struct Params {
  const float* features;
  const float* vertices;
  const float* eb1; const float* eb2; const float* eb3; const float* eb4;
  const float* eb5;
  const float* tb0; const float* tb1; const float* tb2; const float* tb3;
  const float* pb0; const float* pb1; const float* pb2; const float* pb3;
  const float* torigin; const float* scale;
  const ushort* wsb;
  const float* Fg;      // precomputed [8][256] f32
  float* out;
};

__device__ __forceinline__ float silu_f(float x) {
  float e = __expf(-x);
  return x * __builtin_amdgcn_rcpf(1.f + e);
}
__device__ __forceinline__ float sigm_f(float x) {
  return __builtin_amdgcn_rcpf(1.f + __expf(-x));
}
__device__ __forceinline__ ushort f2bf(float f) {
  unsigned u = __float_as_uint(f);
  return (ushort)((u + 0x7fffu + ((u >> 16) & 1u)) >> 16);
}
__device__ __forceinline__ unsigned pack2bf(float a, float b) {
  __hip_bfloat162 h = __float22bfloat162_rn(float2{a, b});
  unsigned u; __builtin_memcpy(&u, &h, 4); return u;
}

// In-place big layer: 8 waves, wave w owns nt = w + s*8 (each weight tile read
// by exactly ONE wave). Internal barrier between read+MFMA and the write
// epilogue makes in-place (single buffer) safe.
template<int KS, int NT_TOT, int INSTR, int OUTSTR>
__device__ __forceinline__ void big_layer_T(const ushort* __restrict__ Wt,
                                            const float* __restrict__ bias,
                                            const ushort* inb, ushort* outb,
                                            int lane, int wv)
{
  constexpr int SLOTS = NT_TOT / 8;
  const int r16 = lane & 15, g = lane >> 4;
  f32x4 acc[SLOTS][4];
  #pragma unroll
  for (int s = 0; s < SLOTS; s++) {
    const int nt = wv + s * 8;
    const float4 bv = *(const float4*)(bias + nt * 16 + g * 4);
    #pragma unroll
    for (int mt = 0; mt < 4; mt++) acc[s][mt] = (f32x4){bv.x, bv.y, bv.z, bv.w};
  }
  #pragma unroll
  for (int k = 0; k < KS; k++) {
    s16x8 bf[4];
    #pragma unroll
    for (int mt = 0; mt < 4; mt++)
      bf[mt] = *(const s16x8*)(inb + (mt * 16 + r16) * INSTR + k * 32 + g * 8);
    #pragma unroll
    for (int s = 0; s < SLOTS; s++) {
      const int nt = wv + s * 8;
      s16x8 aw = *(const s16x8*)(Wt + (size_t)(nt * KS + k) * 512 + lane * 8);
      #pragma unroll
      for (int mt = 0; mt < 4; mt++)
        acc[s][mt] = __builtin_amdgcn_mfma_f32_16x16x32_bf16(aw, bf[mt], acc[s][mt], 0, 0, 0);
    }
  }
  __syncthreads();   // all reads done before anyone writes (in-place safety)
  #pragma unroll
  for (int s = 0; s < SLOTS; s++) {
    const int nt = wv + s * 8;
    #pragma unroll
    for (int mt = 0; mt < 4; mt++) {
      uint2 w;
      w.x = pack2bf(silu_f(acc[s][mt][0]), silu_f(acc[s][mt][1]));
      w.y = pack2bf(silu_f(acc[s][mt][2]), silu_f(acc[s][mt][3]));
      *(uint2*)(outb + (mt * 16 + r16) * OUTSTR + nt * 16 + g * 4) = w;
    }
  }
}

template<int KS, int INSTR>
__device__ __forceinline__ f32x4 tile_mm_T(const ushort* __restrict__ Wt,
                                           const ushort* inb, int mt, int lane, f32x4 binit)
{
  const int r16 = lane & 15, g = lane >> 4;
  f32x4 acc = binit;
  #pragma unroll
  for (int k = 0; k < KS; k++) {
    s16x8 aw = *(const s16x8*)(Wt + k * 512 + lane * 8);
    s16x8 bf = *(const s16x8*)(inb + (mt * 16 + r16) * INSTR + k * 32 + g * 8);
    acc = __builtin_amdgcn_mfma_f32_16x16x32_bf16(aw, bf, acc, 0, 0, 0);
  }
  return acc;
}

__global__ void conv_w(const float* __restrict__ src, ushort* __restrict__ dst,
                       int NT, int KS, int Ksrc, int Kused, int Nused)
{
  int idx = blockIdx.x * 256 + threadIdx.x;
  if (idx >= NT * KS * 512) return;
  int t = idx >> 9, l = (idx >> 3) & 63, i = idx & 7;
  int nt = t / KS, k = t - nt * KS;
  int row = nt * 16 + (l & 15);
  int kk = k * 32 + (l >> 4) * 8 + i;
  float v = (row < Nused && kk < Kused) ? src[row * Ksrc + kk] : 0.f;
  dst[idx] = f2bf(v);
}

// F[b][j] = eb0[j] + sum_i feats[b][i] * ew0[j][78+i]   (f32, once per launch)
__global__ void calc_F(const float* __restrict__ feats, const float* __restrict__ ew0,
                       const float* __restrict__ eb0, float* __restrict__ Fout)
{
  int t = threadIdx.x;
  int b = t >> 5, j0 = (t & 31) * 8;
  for (int jj = 0; jj < 8; jj++) {
    int j = j0 + jj;
    float acc = eb0[j];
    const float* Wr = ew0 + (size_t)j * 131 + 78;
    for (int i = 0; i < 53; i++) acc = fmaf(feats[b * 62 + i], Wr[i], acc);
    Fout[b * 256 + j] = acc;
  }
}

extern "C" __global__ __launch_bounds__(512, 6)
void nbs_kernel(Params P)
{
  extern __shared__ char sm[];
  ushort* actAb  = (ushort*)(sm + L_ACT);
  float*  U      = (float*)(sm + L_U);
  ushort* enc96b = (ushort*)(sm + L_ENC96);
  float*  oencf  = (float*)(sm + L_OENC);
  ushort* a0p    = (ushort*)(sm + L_A0P);
  ushort* a0t    = (ushort*)(sm + L_A0T);
  ushort* tAl    = (ushort*)(sm + L_TA);
  ushort* tBl    = (ushort*)(sm + L_TB);
  ushort* tCl    = (ushort*)(sm + L_TC);
  ushort* featb  = (ushort*)(sm + L_FEATB);
  float*  vertl  = (float*)(sm + L_VERT);
  float*  exprv  = (float*)(sm + L_EXPR);
  float*  tmplv  = (float*)(sm + L_TMPL);
  float*  posew  = (float*)(sm + L_POSW);
  // tail buffers aliased inside act (cols 132+, rows stride 264)
  ushort* ph0b = actAb + 132;   // [64][72]
  ushort* ph1b = actAb + 204;   // [64][40]
  ushort* ph2b = actAb + 132;   // [64][40] (after ph0 dead)

  const int tid  = threadIdx.x;
  const int lane = tid & 63;
  const int wv   = __builtin_amdgcn_readfirstlane(tid >> 6);
  const int r16  = lane & 15, g = lane >> 4;
  const int v0   = blockIdx.x * VPB;
  const ushort* ws = P.wsb;

  // ---- P0: stage featb/vertl, build enc96b (bf16) + oencf (f32) ----
  {
    uint* fbu = (uint*)featb;
    if (tid < 256) {
      int b = tid >> 5, q = tid & 31;
      int e0 = q * 2, e1 = e0 + 1;
      float s0 = (e0 < 62) ? P.features[b * 62 + e0] : 0.f;
      float s1 = (e1 < 62) ? P.features[b * 62 + e1] : 0.f;
      fbu[b * 32 + q] = pack2bf(s0, s1);
    }
    if (tid < VPB * 6) vertl[tid] = P.vertices[(size_t)v0 * 6 + tid];
    // enc96b: [16][96] bf16, rows 0..7 real
    int i2 = tid - 256;   // 0..767 covers 16*48 u32
    if (i2 >= 0 && i2 < 16 * 48) {
      int v = i2 / 48, q = i2 - v * 48;
      float s[2];
      #pragma unroll
      for (int h = 0; h < 2; h++) {
        int e = q * 2 + h;
        float val = 0.f;
        if (v < 8) {
          if (e < 6) val = P.vertices[(size_t)(v0 + v) * 6 + e];
          else if (e < 78) {
            int r = e - 6, k = r / 12, qq = r - k * 12;
            float x = P.vertices[(size_t)(v0 + v) * 6 + (qq < 6 ? qq : qq - 6)] * (float)(1 << k);
            val = (qq < 6) ? __sinf(x) : __cosf(x);
          }
        }
        s[h] = val;
      }
      ((uint*)enc96b)[v * 48 + q] = pack2bf(s[0], s[1]);
    }
    int i3 = tid - 64;    // reuse low-ish threads for oencf (8*24=192)
    if (i3 >= 0 && i3 < 8 * 24) {
      int v = i3 / 24, e = i3 - v * 24;
      float val = 0.f;
      if (e < 3) val = P.vertices[(size_t)(v0 + v) * 6 + e];
      else if (e < 21) {
        int r = e - 3, k = r / 6, q = r - k * 6;
        float x = P.vertices[(size_t)(v0 + v) * 6 + (q < 3 ? q : q - 3)] * (float)(1 << k);
        val = (q < 3) ? __sinf(x) : __cosf(x);
      }
      oencf[i3] = val;
    }
  }
  __syncthreads();

  // ---- P1: U = enc96 @ ew0enc^T  (M=8 verts, K=96, N=256) ----
  {
    #pragma unroll
    for (int s = 0; s < 2; s++) {
      const int nt = wv + s * 8;
      f32x4 acc = (f32x4){0.f, 0.f, 0.f, 0.f};
      #pragma unroll
      for (int k = 0; k < 3; k++) {
        s16x8 aw = *(const s16x8*)(ws + WS_EW0 + (size_t)(nt * 3 + k) * 512 + lane * 8);
        s16x8 bf = *(const s16x8*)(enc96b + r16 * 96 + k * 32 + g * 8);
        acc = __builtin_amdgcn_mfma_f32_16x16x32_bf16(aw, bf, acc, 0, 0, 0);
      }
      if (r16 < 8) *(f32x4*)(U + r16 * 260 + nt * 16 + g * 4) = acc;
    }
  }
  __syncthreads();

  // ---- P2: combine h0 = silu(U[v] + F[b]) -> act (wave w handles v=w) ----
  {
    f32x4 u4 = *(const f32x4*)(U + wv * 260 + lane * 4);
    #pragma unroll 1
    for (int b = 0; b < 8; b++) {
      float4 f4 = *(const float4*)(P.Fg + b * 256 + lane * 4);
      uint2 w;
      w.x = pack2bf(silu_f(u4[0] + f4.x), silu_f(u4[1] + f4.y));
      w.y = pack2bf(silu_f(u4[2] + f4.z), silu_f(u4[3] + f4.w));
      *(uint2*)(actAb + (wv * 8 + b) * 264 + lane * 4) = w;
    }
  }
  __syncthreads();

  // ---- L1..L4 (in-place, internal barrier each) ----
  big_layer_T<8, 16, 264, 264>(ws + WS_EW1, P.eb1, actAb, actAb, lane, wv);
  __syncthreads();
  big_layer_T<8,  8, 264, 264>(ws + WS_EW2, P.eb2, actAb, actAb, lane, wv);
  __syncthreads();
  big_layer_T<4,  8, 264, 264>(ws + WS_EW3, P.eb3, actAb, actAb, lane, wv);
  __syncthreads();
  big_layer_T<4,  8, 264, 264>(ws + WS_EW4, P.eb4, actAb, actAb, lane, wv);
  __syncthreads();

  // ---- PB: build pose/template inputs (U region now dead) ----
  {
    uint* a0pu = (uint*)a0p;          // [64][16 u32]
    ushort* fbs = featb;
    uint* fbu = (uint*)featb;
    for (int idx = tid; idx < 64 * 16; idx += 512) {
      int p = idx >> 4, q = idx & 15, vl = p >> 3, b = p & 7;
      uint u;
      if (q < 10)       u = pack2bf(oencf[vl * 24 + 2 * q], oencf[vl * 24 + 2 * q + 1]);
      else if (q == 10) u = (uint)f2bf(oencf[vl * 24 + 20]) | ((uint)fbs[b * 64 + 53] << 16);
      else if (q == 11) u = fbu[b * 32 + 27];   // feats 54,55
      else if (q == 12) u = fbu[b * 32 + 28];   // feats 56,57
      else if (q == 13) u = (uint)fbs[b * 64 + 58];
      else              u = 0u;
      a0pu[p * 16 + q] = u;
    }
    uint* a0tu = (uint*)a0t;          // [16][16 u32]
    if (tid < 256) {
      int v = tid >> 4, q = tid & 15;
      uint u = 0u;
      if (v < 8) {
        if (q < 10)       u = pack2bf(oencf[v * 24 + 2 * q], oencf[v * 24 + 2 * q + 1]);
        else if (q == 10) u = (uint)f2bf(oencf[v * 24 + 20]);
      }
      a0tu[v * 16 + q] = u;
    }
  }
  __syncthreads();

  // ---- T1: pose L0 (w0-3) | template t0 (w4-7) ----
  if (wv < 4) {
    const int nt = wv;
    const float4 bv = *(const float4*)(P.pb0 + nt * 16 + g * 4);
    #pragma unroll
    for (int mt = 0; mt < 4; mt++) {
      f32x4 d = tile_mm_T<1, 32>(ws + WS_PW0 + nt * 512, a0p, mt, lane,
                                 (f32x4){bv.x, bv.y, bv.z, bv.w});
      uint2 w;
      w.x = pack2bf(silu_f(d[0]), silu_f(d[1]));
      w.y = pack2bf(silu_f(d[2]), silu_f(d[3]));
      *(uint2*)(ph0b + (mt * 16 + r16) * 264 + nt * 16 + g * 4) = w;
    }
  } else {
    const int nt = wv - 4;
    const float4 bv = *(const float4*)(P.tb0 + nt * 16 + g * 4);
    f32x4 d = tile_mm_T<1, 32>(ws + WS_TW0 + nt * 512, a0t, 0, lane,
                               (f32x4){bv.x, bv.y, bv.z, bv.w});
    uint2 w;
    w.x = pack2bf(silu_f(d[0]), silu_f(d[1]));
    w.y = pack2bf(silu_f(d[2]), silu_f(d[3]));
    *(uint2*)(tAl + r16 * 72 + nt * 16 + g * 4) = w;
  }
  __syncthreads();

  // ---- T2: pose L1 (w0-1) | expr L5 (w4-7) | template t1 (w2-3) ----
  if (wv >= 4) {
    const int mt = wv - 4;
    f32x4 bi = (f32x4){0.f, 0.f, 0.f, 0.f};
    if (g == 0) bi = (f32x4){P.eb5[0], P.eb5[1], P.eb5[2], 0.f};
    f32x4 d = tile_mm_T<4, 264>(ws + WS_EW5, actAb, mt, lane, bi);
    if (g == 0) {
      exprv[(mt * 16 + r16) * 3 + 0] = d[0];
      exprv[(mt * 16 + r16) * 3 + 1] = d[1];
      exprv[(mt * 16 + r16) * 3 + 2] = d[2];
    }
  } else if (wv < 2) {
    const int nt = wv;
    const float4 bv = *(const float4*)(P.pb1 + nt * 16 + g * 4);
    #pragma unroll
    for (int mt = 0; mt < 4; mt++) {
      f32x4 d = tile_mm_T<2, 264>(ws + WS_PW1 + nt * 2 * 512, ph0b, mt, lane,
                                 (f32x4){bv.x, bv.y, bv.z, bv.w});
      uint2 w;
      w.x = pack2bf(silu_f(d[0]), silu_f(d[1]));
      w.y = pack2bf(silu_f(d[2]), silu_f(d[3]));
      *(uint2*)(ph1b + (mt * 16 + r16) * 264 + nt * 16 + g * 4) = w;
    }
  } else {
    const int nt = wv - 2;
    const float4 bv = *(const float4*)(P.tb1 + nt * 16 + g * 4);
    f32x4 d = tile_mm_T<2, 72>(ws + WS_TW1 + nt * 2 * 512, tAl, 0, lane,
                               (f32x4){bv.x, bv.y, bv.z, bv.w});
    uint2 w;
    w.x = pack2bf(silu_f(d[0]), silu_f(d[1]));
    w.y = pack2bf(silu_f(d[2]), silu_f(d[3]));
    *(uint2*)(tBl + r16 * 40 + nt * 16 + g * 4) = w;
  }
  __syncthreads();

  // ---- T3: pose L2 (w0-3) | template t2 (w4-5) ----
  if (wv < 4) {
    const int nt = wv >> 1, mt = (wv & 1) * 2;
    const float4 bv = *(const float4*)(P.pb2 + nt * 16 + g * 4);
    #pragma unroll
    for (int m = 0; m < 2; m++) {
      f32x4 d = tile_mm_T<1, 264>(ws + WS_PW2 + nt * 512, ph1b, mt + m, lane,
                                 (f32x4){bv.x, bv.y, bv.z, bv.w});
      uint2 w;
      w.x = pack2bf(silu_f(d[0]), silu_f(d[1]));
      w.y = pack2bf(silu_f(d[2]), silu_f(d[3]));
      *(uint2*)(ph2b + ((mt + m) * 16 + r16) * 264 + nt * 16 + g * 4) = w;
    }
  } else if (wv < 6) {
    const int nt = wv - 4;
    const float4 bv = *(const float4*)(P.tb2 + nt * 16 + g * 4);
    f32x4 d = tile_mm_T<1, 40>(ws + WS_TW2 + nt * 512, tBl, 0, lane,
                               (f32x4){bv.x, bv.y, bv.z, bv.w});
    uint2 w;
    w.x = pack2bf(silu_f(d[0]), silu_f(d[1]));
    w.y = pack2bf(silu_f(d[2]), silu_f(d[3]));
    *(uint2*)(tCl + r16 * 40 + nt * 16 + g * 4) = w;
  }
  __syncthreads();

  // ---- T4: pose L3 -> sigmoid (w0) | template t3 (w1) ----
  if (wv == 0) {
    f32x4 bi = (g == 0) ? (f32x4){P.pb3[0], 0.f, 0.f, 0.f} : (f32x4){0.f, 0.f, 0.f, 0.f};
    #pragma unroll
    for (int mt = 0; mt < 4; mt++) {
      f32x4 d = tile_mm_T<1, 264>(ws + WS_PW3, ph2b, mt, lane, bi);
      if (g == 0) posew[mt * 16 + r16] = sigm_f(d[0]);
    }
  } else if (wv == 1) {
    f32x4 bi = (g == 0) ? (f32x4){P.tb3[0], P.tb3[1], P.tb3[2], 0.f}
                        : (f32x4){0.f, 0.f, 0.f, 0.f};
    f32x4 d = tile_mm_T<1, 40>(ws + WS_TW3, tCl, 0, lane, bi);
    if (g == 0 && r16 < 8) {
      tmplv[r16 * 3 + 0] = d[0];
      tmplv[r16 * 3 + 1] = d[1];
      tmplv[r16 * 3 + 2] = d[2];
    }
  }
  __syncthreads();

  // ---- final transform + store (64 points) ----
  if (tid < 64) {
    int p = tid, vl = p >> 3, b = p & 7;
    float ox = P.torigin[0] * 0.1f, oy = P.torigin[1] * 0.1f, oz = P.torigin[2] * 0.1f;
    float sc = P.scale[0];
    float ev0 = vertl[vl * 6 + 0] + exprv[p * 3 + 0] + tmplv[vl * 3 + 0];
    float ev1 = vertl[vl * 6 + 1] + exprv[p * 3 + 1] + tmplv[vl * 3 + 1];
    float ev2 = vertl[vl * 6 + 2] + exprv[p * 3 + 2] + tmplv[vl * 3 + 2];
    float w = posew[p];
    const float* fb = P.features + b * 62;
    float a0a = fb[53] * w;
    float a1a = fb[54] * w;
    float a2a = fb[55] * w;
    float c1 = __cosf(a0a), s1 = __sinf(a0a);
    float c2 = __cosf(a1a), s2 = __sinf(a1a);
    float c3 = __cosf(a2a), s3 = __sinf(a2a);
    float R00 = c2 * c3,                R01 = -c2 * s3,                R02 = s2;
    float R10 = c1 * s3 + s1 * s2 * c3, R11 = c1 * c3 - s1 * s2 * s3,  R12 = -s1 * c2;
    float R20 = s1 * s3 - c1 * s2 * c3, R21 = s1 * c3 + c1 * s2 * s3,  R22 = c1 * c2;
    float l0 = (ev0 - ox) * sc, l1 = (ev1 - oy) * sc, l2 = (ev2 - oz) * sc;
    float o0 = l0 * R00 + l1 * R10 + l2 * R20 + fb[56] + ox;
    float o1 = l0 * R01 + l1 * R11 + l2 * R21 + fb[57] + oy;
    float o2 = l0 * R02 + l1 * R12 + l2 * R22 + fb[58] + oz;
    size_t o = ((size_t)b * V_TOT + (v0 + vl)) * 3;
    P.out[o + 0] = o0; P.out[o + 1] = o1; P.out[o + 2] = o2;
  }
}

extern "C" void kernel_launch(void* const* d_in, const int* in_sizes, int n_in,
                              void* d_out, int out_size, void* d_ws, size_t ws_size,
                              hipStream_t stream)
{
  (void)in_sizes; (void)n_in; (void)out_size; (void)ws_size;
  ushort* wsp = (ushort*)d_ws;
  float*  Fws = (float*)(wsp + WS_F);

  auto L = [&](const void* s, int woff, int NT, int KS, int Ksrc, int Kused, int Nused) {
    int n = NT * KS * 512;
    hipLaunchKernelGGL(conv_w, dim3((n + 255) / 256), dim3(256), 0, stream,
                       (const float*)s, wsp + woff, NT, KS, Ksrc, Kused, Nused);
  };
  L(d_in[2],  WS_EW0, 16, 3, 131,  78, 256);   // enc part only
  L(d_in[4],  WS_EW1, 16, 8, 256, 256, 256);
  L(d_in[6],  WS_EW2,  8, 8, 256, 256, 128);
  L(d_in[8],  WS_EW3,  8, 4, 128, 128, 128);
  L(d_in[10], WS_EW4,  8, 4, 128, 128, 128);
  L(d_in[12], WS_EW5,  1, 4, 128, 128, 3);
  L(d_in[22], WS_PW0,  4, 1,  27,  27, 64);
  L(d_in[24], WS_PW1,  2, 2,  64,  64, 32);
  L(d_in[26], WS_PW2,  2, 1,  32,  32, 32);
  L(d_in[28], WS_PW3,  1, 1,  32,  32, 1);
  L(d_in[14], WS_TW0,  4, 1,  21,  21, 64);
  L(d_in[16], WS_TW1,  2, 2,  64,  64, 32);
  L(d_in[18], WS_TW2,  2, 1,  32,  32, 32);
  L(d_in[20], WS_TW3,  1, 1,  32,  32, 3);
  hipLaunchKernelGGL(calc_F, dim3(1), dim3(256), 0, stream,
                     (const float*)d_in[1], (const float*)d_in[2],
                     (const float*)d_in[3], Fws);

  Params P;
  P.features = (const float*)d_in[1];
  P.vertices = (const float*)d_in[0];
  P.eb1 = (const float*)d_in[5];
  P.eb2 = (const float*)d_in[7];   P.eb3 = (const float*)d_in[9];
  P.eb4 = (const float*)d_in[11];  P.eb5 = (const float*)d_in[13];
  P.tb0 = (const float*)d_in[15];  P.tb1 = (const float*)d_in[17];
  P.tb2 = (const float*)d_in[19];  P.tb3 = (const float*)d_in[21];
  P.pb0 = (const float*)d_in[23];  P.pb1 = (const float*)d_in[25];
  P.pb2 = (const float*)d_in[27];  P.pb3 = (const float*)d_in[29];
  P.torigin = (const float*)d_in[30];
  P.scale   = (const float*)d_in[31];
  P.wsb = (const ushort*)wsp;
  P.Fg  = (const float*)Fws;
  P.out = (float*)d_out;

  (void)hipFuncSetAttribute((const void*)nbs_kernel,
                            hipFuncAttributeMaxDynamicSharedMemorySize, SMEM_BYTES);
  hipLaunchKernelGGL(nbs_kernel, dim3(NBLK), dim3(512), SMEM_BYTES, stream, P);
}